// Round 2
// baseline (180.065 us; speedup 1.0000x reference)
//
#include <hip/hip_runtime.h>

// net_86698209837440: GNN layer, N=100000 nodes, DEG=32 (tgt = repeat(arange(N),32)
// => edges sorted by target, deg==32 exactly), D=24, NK=2, H=64.
// ALL tensors fp32 (per reference dtypes; R1 NaN proved inputs are not bf16).
// Fused: per-node edge aggregation (2 kernels + mean-norm) -> 48-dim pre -> pre @ W^T.

#define NN   100000
#define DEG  32
#define EE   (NN * DEG)
#define DD   24
#define HH   64
#define NPB  32       // nodes per block; 100000 = 3125 * 32 exactly
#define TPB  256

__global__ __launch_bounds__(TPB) void gnn_fused(
    const float* __restrict__ x,          // [N, 24]
    const int*   __restrict__ edge_index, // [2, E]; row 0 = src
    const float* __restrict__ kv,         // [2, E]
    const float* __restrict__ W,          // [64, 48]
    float*       __restrict__ out)        // [N, 64]
{
    __shared__ float lds_pre[NPB][2 * DD];   // 6 KB

    const int tid  = threadIdx.x;
    const int lane = tid & 63;
    const int wid  = tid >> 6;            // wave 0..3
    const int half = (lane >> 5) & 1;     // half-wave id
    const int hl   = lane & 31;           // lane within half-wave
    const int nodeBase = blockIdx.x * NPB;

    // ---- W row for h = lane into registers: 48 floats via 12 x 16B loads
    float Wreg[2 * DD];
    {
        const float4* wp = (const float4*)W;   // row = 192 B, 16B-aligned
        #pragma unroll
        for (int q = 0; q < 12; ++q) {
            float4 pkt = wp[lane * 12 + q];
            Wreg[q * 4 + 0] = pkt.x;
            Wreg[q * 4 + 1] = pkt.y;
            Wreg[q * 4 + 2] = pkt.z;
            Wreg[q * 4 + 3] = pkt.w;
        }
    }

    const int*   srcA = edge_index;       // src row
    const float* k0   = kv;               // kernel 0
    const float* k1   = kv + EE;          // kernel 1
    const int d     = hl;                 // dim handled by this lane
    const int dsafe = (d < DD) ? d : (DD - 1);  // lanes 24..31 compute junk, never stored

    // ---- Phase 1: aggregation. Each half-wave owns one node; 4 passes x 8 nodes.
    for (int p = 0; p < 4; ++p) {
        const int nl   = p * 8 + wid * 2 + half;
        const int node = nodeBase + nl;
        const int eb   = node * DEG;

        // coalesced prefetch of this node's 32 edges into lanes 0..31 of the half-wave
        const int   sj = srcA[eb + hl];
        const float f0 = k0[eb + hl];
        const float f1 = k1[eb + hl];
        const float xs = x[node * DD + dsafe];

        float a0 = 0.f, a1 = 0.f, sm = 0.f;
        #pragma unroll
        for (int j = 0; j < DEG; ++j) {
            const int   s  = __shfl(sj, j, 32);
            const float c0 = __shfl(f0, j, 32);
            const float c1 = __shfl(f1, j, 32);
            const float xv = x[s * DD + dsafe];
            a0 += c0 * xv;
            a1 += c1 * xv;
            sm += xv;
        }
        if (d < DD) {
            const float m = sm * (1.0f / 32.0f);   // deg == 32 exactly
            lds_pre[nl][d]      = a0 - m + xs;
            lds_pre[nl][DD + d] = a1 - m + xs;
        }
    }
    __syncthreads();

    // ---- Phase 2: out[node][h] = sum_c pre[node][c] * W[h][c]; h = lane.
    for (int q = 0; q < 8; ++q) {
        const int nl = wid + 4 * q;
        const float* pr = lds_pre[nl];   // broadcast reads (conflict-free)
        float acc = 0.f;
        #pragma unroll
        for (int c = 0; c < 2 * DD; ++c) acc += pr[c] * Wreg[c];
        out[(nodeBase + nl) * HH + lane] = acc;
    }
}

extern "C" void kernel_launch(void* const* d_in, const int* in_sizes, int n_in,
                              void* d_out, int out_size, void* d_ws, size_t ws_size,
                              hipStream_t stream) {
    const float* x  = (const float*)d_in[0];
    const int*   ei = (const int*)d_in[1];
    const float* kv = (const float*)d_in[2];
    const float* W  = (const float*)d_in[3];
    float* out = (float*)d_out;

    const int grid = NN / NPB;  // 3125, exact
    gnn_fused<<<grid, TPB, 0, stream>>>(x, ei, kv, W, out);
}